// Round 3
// baseline (162.767 us; speedup 1.0000x reference)
//
#include <hip/hip_runtime.h>
#include <math.h>

constexpr int NH     = 7;
constexpr int NDIST  = 4;
constexpr int NTHETA = 8;
constexpr int EDIM   = 16;
constexpr int NPB    = 8;    // points per block
constexpr int BLOCK  = 256;

typedef float f32x4 __attribute__((ext_vector_type(4)));

__global__ __launch_bounds__(BLOCK) void grid_layer_kernel(
    const float* __restrict__ x,        // (N, 16)
    const float* __restrict__ coords,   // (2, N): [0]=lon, [1]=lat
    const float* __restrict__ sigma_p,  // (1)
    const float* __restrict__ kappa_p,  // (1)
    const int*   __restrict__ lidx,     // (N)
    const int*   __restrict__ adjc,     // (N, 7)
    float*       __restrict__ out,      // (N, 4, 8, 16)
    int N)
{
    __shared__ float4 xs[NPB][NH][EDIM / 4];  // staged neighbor features
    __shared__ float4 vm4[NPB][NH][2];        // vm[t] for t=0..3 / 4..7
    __shared__ float4 nd4[NPB][NH];           // nd[d] for d=0..3
    __shared__ float4 ctr[NPB];               // (lon1, sin(lat1), cos(lat1), -)
    __shared__ int    sidx[NPB][NH];          // neighbor indices

    const int tid = threadIdx.x;
    const int n0  = blockIdx.x * NPB;

    const float inv_s = 1.0f / sigma_p[0];
    const float kappa = kappa_p[0];

    // ---- Phase 1a: stage x neighbors (224 thr) + center trig (8 thr) ----
    if (tid < NPB * NH * 4) {
        const int p  = tid >> 2;
        const int q  = tid & 3;
        const int nl = p / NH;
        const int k  = p - nl * NH;
        const int n  = n0 + nl;
        if (n < N) {
            const int idx = adjc[(size_t)lidx[n] * NH + k];
            if (q == 0) sidx[nl][k] = idx;
            xs[nl][k][q] = ((const float4*)(x + (size_t)idx * EDIM))[q];
        }
    } else if (tid < NPB * NH * 4 + NPB) {
        const int nl = tid - NPB * NH * 4;
        const int n  = n0 + nl;
        if (n < N) {
            const int i0 = adjc[(size_t)lidx[n] * NH];  // center = neighbor 0
            const float lon1 = coords[i0];
            const float lat1 = coords[N + i0];
            float s1, c1;
            __sincosf(lat1, &s1, &c1);
            ctr[nl] = make_float4(lon1, s1, c1, 0.0f);
        }
    }
    __syncthreads();

    // ---- Phase 1b: geometry + ALL weight factors, 56 threads ----
    // phi never materialized: cos(theta_t - phi) expanded via cos/sin(phi).
    // DEGENERACY: for k=0 (and duplicate neighbors) the true bearing args are
    // exactly (0,0) -> atan2(0,0)=0 -> (cphi,sphi)=(1,0). Rounding residues
    // give r2 <= ~4e-17; closest genuine random pair (65536*6 random pairs in
    // a 0.2x0.2 box) has r2 ~ 3e-8. Threshold 1e-12 separates both by >4
    // orders. (Round-0 bug: r2>0 let a +/-half-ulp fma residue set cphi=+/-1,
    // flipping phi to pi on the center neighbor for ~half the points.)
    if (tid < NPB * NH) {
        const int nl = tid / NH;
        const int k  = tid - nl * NH;
        const int n  = n0 + nl;
        if (n < N) {
            const int idxk = sidx[nl][k];
            const float lon2 = coords[idxk];
            const float lat2 = coords[N + idxk];
            const float4 c   = ctr[nl];
            const float sl1 = c.y, cl1 = c.z;
            const float dlon = lon2 - c.x;
            float sl2, cl2, sdl, cdl;
            __sincosf(lat2, &sl2, &cl2);
            __sincosf(dlon, &sdl, &cdl);
            const float tcc  = cl2 * cdl;
            float cosd = fmaf(sl1, sl2, cl1 * tcc);
            cosd = fminf(fmaxf(cosd, -1.0f + 1e-7f), 1.0f - 1e-7f);
            const float dist = acosf(cosd);

            // bearing components; separate products so the degenerate case
            // cancels exactly like the reference (fl(c*s) - fl(s*c) == 0).
            const float p1 = cl1 * sl2;
            const float p2 = sl1 * tcc;
            const float xb = p1 - p2;
            const float yb = sdl * cl2;
            const float r2 = xb * xb + yb * yb;
            float cphi, sphi;
            if (r2 > 1e-12f) {
                const float ri = __builtin_amdgcn_rsqf(r2);
                cphi = xb * ri;
                sphi = yb * ri;
            } else {
                cphi = 1.0f;   // atan2(0,0) = 0
                sphi = 0.0f;
            }

            // vm[t] = exp(kappa*(cos(th_t)cphi + sin(th_t)sphi)), th_t = -pi + t*pi/4
            const float A = kappa * cphi;
            const float B = kappa * sphi;
            const float U = 0.70710678118f * (A + B);
            const float V = 0.70710678118f * (A - B);
            float4 va, vb;
            va.x = __expf(-A); va.y = __expf(-U); va.z = __expf(-B); va.w = __expf(V);
            vb.x = __expf(A);  vb.y = __expf(U);  vb.z = __expf(B);  vb.w = __expf(-V);
            vm4[nl][k][0] = va;
            vm4[nl][k][1] = vb;

            // nd[d] = exp(-0.5*((dp_d - dist)/sigma)^2), dp = {0, .2/3, .4/3, .2}
            const float di = dist * inv_s;
            const float z0 = di;
            const float z1 = fmaf(0.066666667f, inv_s, -di);
            const float z2 = fmaf(0.133333333f, inv_s, -di);
            const float z3 = fmaf(0.2f,         inv_s, -di);
            float4 nd;
            nd.x = __expf(-0.5f * z0 * z0);
            nd.y = __expf(-0.5f * z1 * z1);
            nd.z = __expf(-0.5f * z2 * z2);
            nd.w = __expf(-0.5f * z3 * z3);
            nd4[nl][k] = nd;
        }
    }
    __syncthreads();

    // ---- Phase 2: thread = (n_local, theta, e4) — pure mul/fma ----
    const int nl = tid >> 5;     // 0..7
    const int j  = tid & 31;
    const int t  = j >> 2;       // 0..7
    const int e4 = j & 3;        // 0..3
    const int n  = n0 + nl;
    if (n >= N) return;

    float  sw[NDIST] = {0.f, 0.f, 0.f, 0.f};
    float4 acc[NDIST];
    #pragma unroll
    for (int d = 0; d < NDIST; ++d) acc[d] = make_float4(0.f, 0.f, 0.f, 0.f);

    #pragma unroll
    for (int k = 0; k < NH; ++k) {
        const float  vmk = ((const float*)&vm4[nl][k][0])[t];  // b32, conflict-free
        const float4 nd  = nd4[nl][k];                         // b128 broadcast
        const float4 xv  = xs[nl][k][e4];                      // b128
        const float w0 = vmk * nd.x;
        const float w1 = vmk * nd.y;
        const float w2 = vmk * nd.z;
        const float w3 = vmk * nd.w;
        sw[0] += w0; sw[1] += w1; sw[2] += w2; sw[3] += w3;
        acc[0].x = fmaf(w0, xv.x, acc[0].x);
        acc[0].y = fmaf(w0, xv.y, acc[0].y);
        acc[0].z = fmaf(w0, xv.z, acc[0].z);
        acc[0].w = fmaf(w0, xv.w, acc[0].w);
        acc[1].x = fmaf(w1, xv.x, acc[1].x);
        acc[1].y = fmaf(w1, xv.y, acc[1].y);
        acc[1].z = fmaf(w1, xv.z, acc[1].z);
        acc[1].w = fmaf(w1, xv.w, acc[1].w);
        acc[2].x = fmaf(w2, xv.x, acc[2].x);
        acc[2].y = fmaf(w2, xv.y, acc[2].y);
        acc[2].z = fmaf(w2, xv.z, acc[2].z);
        acc[2].w = fmaf(w2, xv.w, acc[2].w);
        acc[3].x = fmaf(w3, xv.x, acc[3].x);
        acc[3].y = fmaf(w3, xv.y, acc[3].y);
        acc[3].z = fmaf(w3, xv.z, acc[3].z);
        acc[3].w = fmaf(w3, xv.w, acc[3].w);
    }

    // out[n, d, t, e]: lanes j=0..31 write consecutive float4s per d.
    // Nontemporal: 134 MB streamed, never re-read — keep L2 for the x gather.
    float* outp = out + (size_t)n * (NDIST * NTHETA * EDIM);
    #pragma unroll
    for (int d = 0; d < NDIST; ++d) {
        const float inv = __builtin_amdgcn_rcpf(sw[d] + 1e-10f);
        f32x4 o;
        o.x = acc[d].x * inv;
        o.y = acc[d].y * inv;
        o.z = acc[d].z * inv;
        o.w = acc[d].w * inv;
        __builtin_nontemporal_store(
            o, (f32x4*)(outp + (d * NTHETA * EDIM) + (t * EDIM) + e4 * 4));
    }
}

extern "C" void kernel_launch(void* const* d_in, const int* in_sizes, int n_in,
                              void* d_out, int out_size, void* d_ws, size_t ws_size,
                              hipStream_t stream) {
    const float* x      = (const float*)d_in[0];
    const float* coords = (const float*)d_in[1];
    const float* sigma  = (const float*)d_in[2];
    const float* kappa  = (const float*)d_in[3];
    const int*   lidx   = (const int*)d_in[4];
    const int*   adjc   = (const int*)d_in[5];
    float*       out    = (float*)d_out;

    const int N = in_sizes[4];  // local_indices has N elements (B=1)
    const int grid = (N + NPB - 1) / NPB;
    hipLaunchKernelGGL(grid_layer_kernel, dim3(grid), dim3(BLOCK), 0, stream,
                       x, coords, sigma, kappa, lidx, adjc, out, N);
}